// Round 13
// baseline (288.492 us; speedup 1.0000x reference)
//
#include <hip/hip_runtime.h>
#include <hip/hip_bf16.h>
#include <stdint.h>

#define HP 58
#define CIN 256
#define COUT 256
#define HH 56
#define WW 56
#define XROW 14848              // bytes per padded row in xb: 16 slots x 58 x 16B
#define SROW 928                // bytes per slot (58 x 16B)
#define IMG_STRIDE (HP*XROW)    // 861184 B per image
#define NPIX 200704.0           // 64*56*56

// conv LDS: A ring only, 4 slots x 8192 B = 32768 B -> 2 blocks/CU.
// slot layout: [b4][co128][16B], b = ks*2 + (lane>>5)
#define LDS_TOTAL 32768

typedef __attribute__((ext_vector_type(4)))  int i32x4;
typedef __attribute__((ext_vector_type(16))) int i32x16;

#define GLDS(g, l) __builtin_amdgcn_global_load_lds( \
    (const __attribute__((address_space(1))) void*)(g), \
    (__attribute__((address_space(3))) void*)(l), 16, 0, 0)

// ---------- K1: per-(channel,image) partial sums in fp64 (deterministic) ----------
__global__ __launch_bounds__(256) void stats_partial(const float* __restrict__ x,
                                                     double* __restrict__ part) {
  int b = blockIdx.x;            // 256*64
  int c = b >> 6, n = b & 63;
  const float4* p = (const float4*)(x + (size_t)(n*CIN + c) * (HH*WW));
  double s = 0.0, s2 = 0.0;
  for (int i = threadIdx.x; i < 784; i += 256) {
    float4 v = p[i];
    double a0 = v.x, a1 = v.y, a2 = v.z, a3 = v.w;
    s  += (a0 + a1) + (a2 + a3);
    s2 += (a0*a0 + a1*a1) + (a2*a2 + a3*a3);
  }
  for (int off = 32; off > 0; off >>= 1) {
    s  += __shfl_down(s, off);
    s2 += __shfl_down(s2, off);
  }
  __shared__ double red[8];
  int wv = threadIdx.x >> 6, ln = threadIdx.x & 63;
  if (ln == 0) { red[wv*2] = s; red[wv*2+1] = s2; }
  __syncthreads();
  if (threadIdx.x == 0) {
    double ts = ((red[0]+red[2])+red[4])+red[6];
    double t2 = ((red[1]+red[3])+red[5])+red[7];
    part[(size_t)(c*64 + n)*2]     = ts;
    part[(size_t)(c*64 + n)*2 + 1] = t2;
  }
}

// ---------- K2: finalize per-channel {mean, gamma*inv_std, beta} in fp64 ----------
__global__ void stats_final(const double* __restrict__ part,
                            const float* __restrict__ gamma,
                            const float* __restrict__ beta,
                            double* __restrict__ prm) {
  int c = threadIdx.x;
  double s = 0.0, s2 = 0.0;
  for (int n = 0; n < 64; ++n) {
    s  += part[(size_t)(c*64+n)*2];
    s2 += part[(size_t)(c*64+n)*2 + 1];
  }
  double mean = s / NPIX;
  double var  = s2 / NPIX - mean*mean;
  double inv  = 1.0 / sqrt(var + 1e-5);
  prm[c*4+0] = mean;
  prm[c*4+1] = (double)gamma[c] * inv;
  prm[c*4+2] = (double)beta[c];
}

// ---------- K3: binarize -> xb[n][y][slot16][x58][16B] int8 ----------
__global__ __launch_bounds__(256) void binarize(const float* __restrict__ x,
                                                const double* __restrict__ prm,
                                                int8_t* __restrict__ xb) {
  int b = blockIdx.x;            // 64*58
  int n = b / HP, y = b % HP;
  int8_t* orow = xb + (size_t)(n*HP + y) * XROW;
  if (y == 0 || y == HP-1) {     // zero padding rows: 14848 B
    int4 z = {0,0,0,0};
    int4* q = (int4*)orow;
    for (int i = threadIdx.x; i < XROW/16; i += 256) q[i] = z;
    return;
  }
  __shared__ char sbuf[WW][260];   // odd dword stride -> conflict-free
  int h  = y - 1;
  int tid = threadIdx.x;
  #pragma unroll
  for (int it = 0; it < 14; ++it) {        // 14*256 = 3584 = 256c * 14 float4
    int t = it*256 + tid;
    int c = t / 14, j = t - c*14;
    float4 v = *(const float4*)(x + (size_t)(n*CIN + c)*(HH*WW) + h*WW + j*4);
    double mu = prm[c*4], gi = prm[c*4+1], be = prm[c*4+2];
    #pragma unroll
    for (int e = 0; e < 4; ++e) {
      double xv = (double)((&v.x)[e]);
      double vv = (xv - mu)*gi + be;
      sbuf[j*4+e][c] = vv > 0.0 ? (int8_t)1 : (vv < 0.0 ? (int8_t)-1 : (int8_t)0);
    }
  }
  __syncthreads();
  for (int u = tid; u < 16*58; u += 256) {
    int slot = u / 58, xx = u - slot*58;
    int4 v = {0,0,0,0};
    if (xx >= 1 && xx <= WW) {
      const uint32_t* src = (const uint32_t*)&sbuf[xx-1][slot*16];
      v.x = src[0]; v.y = src[1]; v.z = src[2]; v.w = src[3];
    }
    *(int4*)(orow + u*16) = v;
  }
}

// ---------- K4: quantize W -> Wbr[step36][ch2][b4][co128][16B] i8, per-co scale ----------
// step = tap*4 + q (64-ci quarter); b = ks*2 + half (ci = q*64 + ks*32 + half*16 + r)
__global__ __launch_bounds__(256) void wrepack(const float* __restrict__ W,
                                               int8_t* __restrict__ Wbr,
                                               float* __restrict__ invs) {
  int co = blockIdx.x, ci = threadIdx.x;
  float w[9]; float mx = 0.f;
  const float* p = W + (size_t)co*(CIN*9) + ci*9;
  #pragma unroll
  for (int t = 0; t < 9; ++t) { w[t] = p[t]; mx = fmaxf(mx, fabsf(w[t])); }
  for (int off = 32; off > 0; off >>= 1) mx = fmaxf(mx, __shfl_xor(mx, off));
  __shared__ float sm[4];
  if ((threadIdx.x & 63) == 0) sm[threadIdx.x >> 6] = mx;
  __syncthreads();
  mx = fmaxf(fmaxf(sm[0], sm[1]), fmaxf(sm[2], sm[3]));
  float s = mx > 0.f ? 127.f / mx : 0.f;
  int q = ci >> 6, ks = (ci >> 5) & 1, half = (ci >> 4) & 1, r = ci & 15;
  int ch = co >> 7, col = co & 127;
  int off = ch*8192 + (ks*2 + half)*2048 + col*16 + r;
  #pragma unroll
  for (int t = 0; t < 9; ++t) {
    int qv = (int)lrintf(w[t] * s);
    qv = qv > 127 ? 127 : (qv < -127 ? -127 : qv);
    Wbr[(t*4 + q)*16384 + off] = (int8_t)qv;
  }
  if (threadIdx.x == 0) invs[co] = mx / 127.f;
}

// ---------- K5: implicit-GEMM conv, i8 32x32x32. 2 blocks/CU; B direct global ----------
// 1792 blocks x 512 thr; tile 128co x 4rows x 64xx; 8 waves = 2wm x 4wn; wave 64co x 64xx.
// Per step s: vmcnt(5) [retires STAGE(s) etc; newest 5 = STAGE(s+2)+B(s)]; barrier;
// STAGE(s+3) [1 GLDS]; B(s+1) [4 global dwordx4, 512B-coalesced]; 4 ds_read A(s);
// 8 mfma_i32_32x32x32_i8. acc[2][2]=64 VGPR; target <=128 total for 4 waves/SIMD.
__global__ __launch_bounds__(512, 4) void conv_gemm(const int8_t* __restrict__ xb,
                                                    const int8_t* __restrict__ Wbr,
                                                    const float* __restrict__ invs,
                                                    float* __restrict__ out) {
  extern __shared__ char smem[];
  int bid = blockIdx.x;
  int swz = (bid & 7) * 224 + (bid >> 3);    // XCD-aware, bijective (1792 % 8 == 0)
  int ch = swz & 1;                          // co half; pairs share rows -> L2 reuse
  int g  = swz >> 1;                         // 0..895
  int img = g / 14, rg = g - img*14;
  int y0 = 1 + rg*4;                         // output rows y0..y0+3 (padded coords)

  int tid = threadIdx.x;
  int ln = tid & 63, wid = tid >> 6;
  int wm = wid >> 2, wn = wid & 3;           // wm: 64co slice, wn: y-row

  // B global base: row y0-1+wn (+kh via su), slot lane>>5, x = (ln&31)-1 (+nt*32+kw)
  const int8_t* xg = xb + (size_t)img*IMG_STRIDE + (size_t)(y0 - 1 + wn)*XROW
                        + (ln >> 5)*SROW + ((ln & 31) - 1)*16;
  // A LDS read base: slot + ks*4096 + (ln>>5)*2048 + co*16
  const char* vA = smem + ((ln >> 5) << 11) + (wm*64 + (ln & 31))*16;

  const int8_t* stSrc = Wbr + ch*8192 + tid*16;
  char*         stDst = smem + tid*16;

#define STG(S) do { if ((S) < 36) GLDS(stSrc + (S)*16384, stDst + ((S) & 3)*8192); } while (0)

  i32x4 a[2][2], b0[2][2], b1[2][2];
  i32x16 acc[2][2] = {};

#define BLOAD(SU, BV) do { \
    BV[0][0] = *(const i32x4*)(xg + (SU)); \
    BV[0][1] = *(const i32x4*)(xg + (SU) + 1856); \
    BV[1][0] = *(const i32x4*)(xg + (SU) + 512); \
    BV[1][1] = *(const i32x4*)(xg + (SU) + 2368); \
  } while (0)

#define ALOAD(S) do { const char* _ab = vA + ((S) & 3)*8192; \
    a[0][0] = *(const i32x4*)(_ab);        a[0][1] = *(const i32x4*)(_ab + 4096); \
    a[1][0] = *(const i32x4*)(_ab + 512);  a[1][1] = *(const i32x4*)(_ab + 4608); \
  } while (0)

#define MF(BV) do { \
    __builtin_amdgcn_s_setprio(1); \
    _Pragma("unroll") \
    for (int _ks = 0; _ks < 2; ++_ks) \
      _Pragma("unroll") \
      for (int _mt = 0; _mt < 2; ++_mt) \
        _Pragma("unroll") \
        for (int _nt = 0; _nt < 2; ++_nt) \
          acc[_mt][_nt] = __builtin_amdgcn_mfma_i32_32x32x32_i8(a[_mt][_ks], BV[_nt][_ks], \
                                                                acc[_mt][_nt], 0, 0, 0); \
    __builtin_amdgcn_s_setprio(0); \
  } while (0)

#define VM5 do { \
    asm volatile("s_waitcnt vmcnt(5)" ::: "memory"); \
    __builtin_amdgcn_s_barrier(); \
  } while (0)

  // prologue: stage slots 0..2, load B(0)
  STG(0); STG(1); STG(2);
  BLOAD(0, b0);

  #pragma unroll 1
  for (int t = 0; t < 9; ++t) {
    int kh = (t*11) >> 5, kw = t - kh*3;
    int su = kh*XROW + kw*16;
    int t1 = t < 8 ? t + 1 : 8;
    int kh1 = (t1*11) >> 5, kw1 = t1 - kh1*3;
    int sun = kh1*XROW + kw1*16;

    VM5; STG(4*t+3); BLOAD(su +  3712, b1); ALOAD(4*t  ); MF(b0);   // s = 4t
    VM5; STG(4*t+4); BLOAD(su +  7424, b0); ALOAD(4*t+1); MF(b1);   // s = 4t+1
    VM5; STG(4*t+5); BLOAD(su + 11136, b1); ALOAD(4*t+2); MF(b0);   // s = 4t+2
    VM5; STG(4*t+6);
    if (t < 8) BLOAD(sun, b0);
    ALOAD(4*t+3); MF(b1);                                           // s = 4t+3
  }

  // ---- epilogue: direct coalesced stores. C: col=ln&31 -> xx, row=(r&3)+8(r>>2)+4(ln>>5) ----
  int y_out = y0 + wn - 1;
  size_t ob0 = ((size_t)img * COUT)*(HH*WW) + (size_t)y_out*WW;
  #pragma unroll
  for (int mt = 0; mt < 2; ++mt) {
    int cb0 = ch*128 + wm*64 + mt*32 + ((ln >> 5) << 2);
    float4 iv[4];
    #pragma unroll
    for (int q = 0; q < 4; ++q) iv[q] = *(const float4*)(invs + cb0 + 8*q);
    #pragma unroll
    for (int nt = 0; nt < 2; ++nt) {
      int xx = nt*32 + (ln & 31);
      bool ok = (xx >= 1) && (xx <= WW);
      size_t ob = ob0 + (xx - 1);
      #pragma unroll
      for (int r = 0; r < 16; ++r) {
        int q = r >> 2, rr = r & 3;
        int co = cb0 + 8*q + rr;
        float v = fmaxf((float)acc[mt][nt][r] * ((&iv[q].x)[rr]), 0.0f);
        if (ok) out[ob + (size_t)co*(HH*WW)] = v;
      }
    }
  }
}

extern "C" void kernel_launch(void* const* d_in, const int* in_sizes, int n_in,
                              void* d_out, int out_size, void* d_ws, size_t ws_size,
                              hipStream_t stream) {
  const float* x     = (const float*)d_in[0];
  const float* gamma = (const float*)d_in[1];
  const float* beta  = (const float*)d_in[2];
  const float* W     = (const float*)d_in[3];
  float* out = (float*)d_out;

  char* ws = (char*)d_ws;
  // layout: part [262144] | prm [8192] | invs [1024] | Wbr i8 [589824] | pad | xb i8 @1MiB
  double*  part = (double*)ws;
  double*  prm  = (double*)(ws + 262144);
  float*   invs = (float*)(ws + 270336);
  int8_t*  Wbr  = (int8_t*)(ws + 271360);
  int8_t*  xbuf = (int8_t*)(ws + 1048576);
  // xb: 64*58*14848 = 55,115,776 B (±16B over-read slack within ws)

  (void)hipFuncSetAttribute((const void*)conv_gemm,
                            hipFuncAttributeMaxDynamicSharedMemorySize, LDS_TOTAL);

  hipLaunchKernelGGL(wrepack,       dim3(256),    dim3(256), 0, stream, W, Wbr, invs);
  hipLaunchKernelGGL(stats_partial, dim3(256*64), dim3(256), 0, stream, x, part);
  hipLaunchKernelGGL(stats_final,   dim3(1),      dim3(256), 0, stream, part, gamma, beta, prm);
  hipLaunchKernelGGL(binarize,      dim3(64*HP),  dim3(256), 0, stream, x, prm, xbuf);
  hipLaunchKernelGGL(conv_gemm,     dim3(1792),   dim3(512), LDS_TOTAL, stream, xbuf, Wbr, invs, out);
}

// Round 14
// 266.056 us; speedup vs baseline: 1.0843x; 1.0843x over previous
//
#include <hip/hip_runtime.h>
#include <hip/hip_bf16.h>
#include <stdint.h>

#define HP 58
#define CIN 256
#define COUT 256
#define HH 56
#define WW 56
#define XROW 14848              // bytes per padded row in xb: 16 slots x 58 x 16B
#define SROW 928
#define IMG_STRIDE (HP*XROW)    // 861184 B per image
#define NPIX 200704.0           // 64*56*56

// conv LDS layout (dynamic, 155136 B):
//   [0,16)           front guard (x_in = -1, slot 0, row 0)
//   [16,89104)       X: 6 rows x 16 slots x 58 x 16B (row stride 14848, slot stride 928)
//   [89104,89600)    tail slack (x_in up to 64 bleeds reads here: discarded outputs)
//   [89600,155136)   A ring: 4 x 16384 (ks*8192 + slotL*4096 + co*16)
#define XO    16
#define AO    89600
#define LDS_TOTAL 155136

typedef __attribute__((ext_vector_type(4)))  int i32x4;
typedef __attribute__((ext_vector_type(16))) int i32x16;

#define GLDS(g, l) __builtin_amdgcn_global_load_lds( \
    (const __attribute__((address_space(1))) void*)(g), \
    (__attribute__((address_space(3))) void*)(l), 16, 0, 0)

// ---------- K1 (fused): stats_partial (blocks 0..16383) + wrepack (blocks 16384..16639) ----
__global__ __launch_bounds__(256) void prep_a(const float* __restrict__ x,
                                              double* __restrict__ part,
                                              const float* __restrict__ W,
                                              int8_t* __restrict__ Wbr,
                                              float* __restrict__ invs) {
  if (blockIdx.x < 16384) {
    // ---- per-(channel,image) partial sums in fp64 (deterministic) ----
    int b = blockIdx.x;            // 256*64
    int c = b >> 6, n = b & 63;
    const float4* p = (const float4*)(x + (size_t)(n*CIN + c) * (HH*WW));
    double s = 0.0, s2 = 0.0;
    for (int i = threadIdx.x; i < 784; i += 256) {
      float4 v = p[i];
      double a0 = v.x, a1 = v.y, a2 = v.z, a3 = v.w;
      s  += (a0 + a1) + (a2 + a3);
      s2 += (a0*a0 + a1*a1) + (a2*a2 + a3*a3);
    }
    for (int off = 32; off > 0; off >>= 1) {
      s  += __shfl_down(s, off);
      s2 += __shfl_down(s2, off);
    }
    __shared__ double red[8];
    int wv = threadIdx.x >> 6, ln = threadIdx.x & 63;
    if (ln == 0) { red[wv*2] = s; red[wv*2+1] = s2; }
    __syncthreads();
    if (threadIdx.x == 0) {
      double ts = ((red[0]+red[2])+red[4])+red[6];
      double t2 = ((red[1]+red[3])+red[5])+red[7];
      part[(size_t)(c*64 + n)*2]     = ts;
      part[(size_t)(c*64 + n)*2 + 1] = t2;
    }
  } else {
    // ---- quantize W -> Wbr[step36][b4][co256][16B] i8, per-co scale ----
    int co = blockIdx.x - 16384, ci = threadIdx.x;
    float w[9]; float mx = 0.f;
    const float* p = W + (size_t)co*(CIN*9) + ci*9;
    #pragma unroll
    for (int t = 0; t < 9; ++t) { w[t] = p[t]; mx = fmaxf(mx, fabsf(w[t])); }
    for (int off = 32; off > 0; off >>= 1) mx = fmaxf(mx, __shfl_xor(mx, off));
    __shared__ float sm[4];
    if ((threadIdx.x & 63) == 0) sm[threadIdx.x >> 6] = mx;
    __syncthreads();
    mx = fmaxf(fmaxf(sm[0], sm[1]), fmaxf(sm[2], sm[3]));
    float s = mx > 0.f ? 127.f / mx : 0.f;
    int off = ((ci >> 6) * 4 + ((ci >> 4) & 3)) * 4096 + co*16 + (ci & 15);
    #pragma unroll
    for (int t = 0; t < 9; ++t) {
      int qv = (int)lrintf(w[t] * s);
      qv = qv > 127 ? 127 : (qv < -127 ? -127 : qv);
      Wbr[t*65536 + off] = (int8_t)qv;
    }
    if (threadIdx.x == 0) invs[co] = mx / 127.f;
  }
}

// ---------- K2: finalize per-channel {mean, gamma*inv_std, beta}; 256 blocks x 1 wave ----
__global__ __launch_bounds__(64) void stats_final(const double* __restrict__ part,
                                                  const float* __restrict__ gamma,
                                                  const float* __restrict__ beta,
                                                  double* __restrict__ prm) {
  int c = blockIdx.x, ln = threadIdx.x;
  double s  = part[(size_t)(c*64 + ln)*2];
  double s2 = part[(size_t)(c*64 + ln)*2 + 1];
  for (int off = 32; off > 0; off >>= 1) {
    s  += __shfl_down(s, off);
    s2 += __shfl_down(s2, off);
  }
  if (ln == 0) {
    double mean = s / NPIX;
    double var  = s2 / NPIX - mean*mean;
    double inv  = 1.0 / sqrt(var + 1e-5);
    prm[c*4+0] = mean;
    prm[c*4+1] = (double)gamma[c] * inv;
    prm[c*4+2] = (double)beta[c];
  }
}

// ---------- K3: binarize -> xb[n][y][slot16][x58][16B] int8 ----------
__global__ __launch_bounds__(256) void binarize(const float* __restrict__ x,
                                                const double* __restrict__ prm,
                                                int8_t* __restrict__ xb) {
  int b = blockIdx.x;            // 64*58
  int n = b / HP, y = b % HP;
  int8_t* orow = xb + (size_t)(n*HP + y) * XROW;
  if (y == 0 || y == HP-1) {     // zero padding rows: 14848 B
    int4 z = {0,0,0,0};
    int4* q = (int4*)orow;
    for (int i = threadIdx.x; i < XROW/16; i += 256) q[i] = z;
    return;
  }
  __shared__ char sbuf[WW][260];   // odd dword stride -> conflict-free
  int h  = y - 1;
  int tid = threadIdx.x;
  #pragma unroll
  for (int it = 0; it < 14; ++it) {        // 14*256 = 3584 = 256c * 14 float4
    int t = it*256 + tid;
    int c = t / 14, j = t - c*14;
    float4 v = *(const float4*)(x + (size_t)(n*CIN + c)*(HH*WW) + h*WW + j*4);
    double mu = prm[c*4], gi = prm[c*4+1], be = prm[c*4+2];
    #pragma unroll
    for (int e = 0; e < 4; ++e) {
      double xv = (double)((&v.x)[e]);
      double vv = (xv - mu)*gi + be;
      sbuf[j*4+e][c] = vv > 0.0 ? (int8_t)1 : (vv < 0.0 ? (int8_t)-1 : (int8_t)0);
    }
  }
  __syncthreads();
  for (int u = tid; u < 16*58; u += 256) {
    int slot = u / 58, xx = u - slot*58;
    int4 v = {0,0,0,0};
    if (xx >= 1 && xx <= WW) {
      const uint32_t* src = (const uint32_t*)&sbuf[xx-1][slot*16];
      v.x = src[0]; v.y = src[1]; v.z = src[2]; v.w = src[3];
    }
    *(int4*)(orow + u*16) = v;
  }
}

// ---------- K5: implicit-GEMM conv, i8 32x32x32; tap-unrolled, literal-offset ds_reads ----
// (exact R10 champion: 154.9 us, MfmaUtil 38, conflicts 0)
__global__ __launch_bounds__(512, 2) void conv_gemm(const int8_t* __restrict__ xb,
                                                    const int8_t* __restrict__ Wbr,
                                                    const float* __restrict__ invs,
                                                    float* __restrict__ out) {
  extern __shared__ char smem[];
  int bid = blockIdx.x;
  int swz = (bid & 7) * 112 + (bid >> 3);    // XCD-aware, bijective (896 % 8 == 0)
  int n_img = swz / 14, rg = swz - n_img * 14;
  int y0 = 1 + rg * 4;                       // output rows y0..y0+3 (padded coords)

  int tid = threadIdx.x;
  int ln = tid & 63, wid = tid >> 6;
  int wm = wid >> 2, wn = wid & 3;           // wm: co half, wn: y-row

  size_t xoff = (size_t)n_img * IMG_STRIDE + (size_t)(y0 - 1) * XROW;

  // ---- prologue: stage X once, pure linear copy (6 rows x 14848 B = 89088 B) ----
  #pragma unroll
  for (int i = 0; i < 11; ++i) {
    int o = tid*16 + i*8192;
    if (o < 6*XROW)                          // 89088 = 87*1024: wave-uniform guard
      GLDS(xb + xoff + o, smem + XO + o);
  }

  const int8_t* stSrc = Wbr + tid*16;
  char*         stDst = smem + AO + tid*16;
#define STAGE(SCOFF, BUFQ) do { \
    const int8_t* _s = stSrc + (SCOFF); \
    char* _d = stDst + (BUFQ)*16384; \
    GLDS(_s, _d); GLDS(_s + 8192, _d + 8192); \
  } while (0)

  i32x16 acc[4][2] = {};
  STAGE(0, 0); STAGE(16384, 1); STAGE(32768, 2);

  // invariant read bases
  const char* vA = smem + AO + ((ln >> 5) << 12) + (wm*128 + (ln & 31)) * 16;
  const char* vX = smem + XO + wn*XROW + (ln >> 5)*SROW + ((ln & 31) - 1) * 16;

  i32x4 aA[4][2], bA[2][2], aB[4][2], bB[2][2];

#define LOADF(Q, SU, AV, BV) do { \
    const char* _ab = vA + (Q)*16384; \
    AV[0][0] = *(const i32x4*)(_ab +    0); AV[0][1] = *(const i32x4*)(_ab + 8192); \
    AV[1][0] = *(const i32x4*)(_ab +  512); AV[1][1] = *(const i32x4*)(_ab + 8704); \
    AV[2][0] = *(const i32x4*)(_ab + 1024); AV[2][1] = *(const i32x4*)(_ab + 9216); \
    AV[3][0] = *(const i32x4*)(_ab + 1536); AV[3][1] = *(const i32x4*)(_ab + 9728); \
    const char* _bb = vX + (SU); \
    BV[0][0] = *(const i32x4*)(_bb +    0); BV[0][1] = *(const i32x4*)(_bb + 1856); \
    BV[1][0] = *(const i32x4*)(_bb +  512); BV[1][1] = *(const i32x4*)(_bb + 2368); \
  } while (0)

#define MFMA_ALL(AV, BV) do { \
    __builtin_amdgcn_s_setprio(1); \
    _Pragma("unroll") \
    for (int ks = 0; ks < 2; ++ks) \
      _Pragma("unroll") \
      for (int mt = 0; mt < 4; ++mt) \
        _Pragma("unroll") \
        for (int nt = 0; nt < 2; ++nt) \
          acc[mt][nt] = __builtin_amdgcn_mfma_i32_32x32x32_i8(AV[mt][ks], BV[nt][ks], \
                                                              acc[mt][nt], 0, 0, 0); \
    __builtin_amdgcn_s_setprio(0); \
  } while (0)

#define VMB do { \
    asm volatile("s_waitcnt vmcnt(2)" ::: "memory"); \
    __builtin_amdgcn_s_barrier(); \
  } while (0)

  // prologue wait: X + A(0) landed (A1,A2 = 4 loads outstanding), then block sync
  asm volatile("s_waitcnt vmcnt(4)" ::: "memory");
  __builtin_amdgcn_s_barrier();
  LOADF(0, 0, aA, bA);

  #pragma unroll 1
  for (int t = 0; t < 9; ++t) {
    int kh0 = (t * 11) >> 5,  kw0 = t - kh0*3;
    int t1  = t < 8 ? t + 1 : 8;
    int kh1 = (t1 * 11) >> 5, kw1 = t1 - kh1*3;
    int su0 = kh0*XROW + kw0*16;
    int su1 = su0 + 3712, su2 = su0 + 7424, su3 = su0 + 11136;
    int su4 = kh1*XROW + kw1*16;
    int sA  = 4*t;
    int sc3 = (sA+3 < 36 ? sA+3 : 35) * 16384;
    int sc4 = (sA+4 < 36 ? sA+4 : 35) * 16384;
    int sc5 = (sA+5 < 36 ? sA+5 : 35) * 16384;
    int sc6 = (sA+6 < 36 ? sA+6 : 35) * 16384;

    VMB; STAGE(sc3, 3); LOADF(1, su1, aB, bB); MFMA_ALL(aA, bA);   // step 4t+0
    VMB; STAGE(sc4, 0); LOADF(2, su2, aA, bA); MFMA_ALL(aB, bB);   // step 4t+1
    VMB; STAGE(sc5, 1); LOADF(3, su3, aB, bB); MFMA_ALL(aA, bA);   // step 4t+2
    VMB; STAGE(sc6, 2); LOADF(0, su4, aA, bA); MFMA_ALL(aB, bB);   // step 4t+3
  }
  asm volatile("s_waitcnt vmcnt(0)" ::: "memory");     // drain tail GLDS before exit

  // ---- epilogue: direct coalesced stores. C: col=ln&31 -> xx, row=(r&3)+8(r>>2)+4(ln>>5) ----
  int y_out = y0 + wn - 1;
  size_t ob0 = ((size_t)n_img * COUT) * (HH*WW) + (size_t)y_out * WW;
  #pragma unroll
  for (int mt = 0; mt < 4; ++mt) {
    int cb0 = wm*128 + mt*32 + ((ln >> 5) << 2);
    float4 iv[4];
    #pragma unroll
    for (int q = 0; q < 4; ++q) iv[q] = *(const float4*)(invs + cb0 + 8*q);
    #pragma unroll
    for (int nt = 0; nt < 2; ++nt) {
      int xx = nt*32 + (ln & 31);
      bool ok = (xx >= 1) && (xx <= WW);
      size_t ob = ob0 + (xx - 1);
      #pragma unroll
      for (int r = 0; r < 16; ++r) {
        int q = r >> 2, rr = r & 3;
        int co = cb0 + 8*q + rr;
        float v = fmaxf((float)acc[mt][nt][r] * ((&iv[q].x)[rr]), 0.0f);
        if (ok) out[ob + (size_t)co * (HH*WW)] = v;
      }
    }
  }
}

extern "C" void kernel_launch(void* const* d_in, const int* in_sizes, int n_in,
                              void* d_out, int out_size, void* d_ws, size_t ws_size,
                              hipStream_t stream) {
  const float* x     = (const float*)d_in[0];
  const float* gamma = (const float*)d_in[1];
  const float* beta  = (const float*)d_in[2];
  const float* W     = (const float*)d_in[3];
  float* out = (float*)d_out;

  char* ws = (char*)d_ws;
  // layout: part [262144] | prm [8192] | invs [1024] | Wbr i8 [589824] | pad | xb i8 @1MiB
  double*  part = (double*)ws;
  double*  prm  = (double*)(ws + 262144);
  float*   invs = (float*)(ws + 270336);
  int8_t*  Wbr  = (int8_t*)(ws + 271360);
  int8_t*  xbuf = (int8_t*)(ws + 1048576);
  // xb: 64*58*14848 = 55,115,776 B

  (void)hipFuncSetAttribute((const void*)conv_gemm,
                            hipFuncAttributeMaxDynamicSharedMemorySize, LDS_TOTAL);

  hipLaunchKernelGGL(prep_a,      dim3(16640), dim3(256), 0, stream, x, part, W, Wbr, invs);
  hipLaunchKernelGGL(stats_final, dim3(256),   dim3(64),  0, stream, part, gamma, beta, prm);
  hipLaunchKernelGGL(binarize,    dim3(64*HP), dim3(256), 0, stream, x, prm, xbuf);
  hipLaunchKernelGGL(conv_gemm,   dim3(896),   dim3(512), LDS_TOTAL, stream, xbuf, Wbr, invs, out);
}